// Round 4
// baseline (442.950 us; speedup 1.0000x reference)
//
#include <hip/hip_runtime.h>
#include <stdint.h>

typedef unsigned int u32;

__device__ __forceinline__ float lrelu(float x){ return x > 0.f ? x : 0.2f*x; }

// ---------------- CSR build ----------------
__global__ void k_hist(const int* __restrict__ dst, int* __restrict__ deg, int E){
  int e = blockIdx.x*blockDim.x + threadIdx.x;
  if (e < E) atomicAdd(&deg[dst[e]], 1);
}

__global__ void k_scan1(const int* __restrict__ deg, int* __restrict__ offs,
                        int* __restrict__ bsum, int n){
  __shared__ int lds[256];
  int t = threadIdx.x;
  int base = blockIdx.x*1024 + t*4;
  int v0 = (base+0<n)?deg[base+0]:0;
  int v1 = (base+1<n)?deg[base+1]:0;
  int v2 = (base+2<n)?deg[base+2]:0;
  int v3 = (base+3<n)?deg[base+3]:0;
  int s = v0+v1+v2+v3;
  lds[t] = s; __syncthreads();
  for (int off=1; off<256; off<<=1){
    int tmp = (t>=off)? lds[t-off] : 0;
    __syncthreads();
    lds[t] += tmp;
    __syncthreads();
  }
  int excl = lds[t] - s;
  if (t==255) bsum[blockIdx.x] = lds[255];
  if (base+0<n) offs[base+0] = excl;
  if (base+1<n) offs[base+1] = excl+v0;
  if (base+2<n) offs[base+2] = excl+v0+v1;
  if (base+3<n) offs[base+3] = excl+v0+v1+v2;
}

__global__ void k_scan2(int* bsum, int nb){
  int lane = threadIdx.x;
  int v = (lane<nb)? bsum[lane] : 0;
  int orig = v;
  for (int off=1; off<64; off<<=1){
    int t = __shfl_up(v, off);
    if (lane >= off) v += t;
  }
  if (lane<nb) bsum[lane] = v - orig;   // exclusive
}

__global__ void k_scan3(int* __restrict__ offs, int* __restrict__ cur,
                        const int* __restrict__ bsum, int n){
  int i = blockIdx.x*blockDim.x + threadIdx.x;
  if (i<n){ int v = offs[i] + bsum[i>>10]; offs[i]=v; cur[i]=v; }
}

__global__ void k_scatter(const int* __restrict__ src, const int* __restrict__ dst,
                          int* __restrict__ cur, int* __restrict__ adj, int E){
  int e = blockIdx.x*blockDim.x + threadIdx.x;
  if (e<E){
    int d = dst[e];
    int p = atomicAdd(&cur[d], 1);
    adj[p] = src[e];
  }
}

// ---------------- GEMM: H = X @ W  (FIN=128, f32 in / f32 out) ----------------
template<int FOUT>
__global__ void k_gemm(const float* __restrict__ X, const float* __restrict__ W,
                       float* __restrict__ H, int N){
  constexpr int FIN = 128, ROWS = 16;
  __shared__ float xs[ROWS*FIN];
  int t = threadIdx.x;
  long i0 = (long)blockIdx.x*ROWS;   // N % 16 == 0 (50000 = 16*3125)
  {
    const float4* xsrc = (const float4*)(X + i0*FIN);   // 512 float4s per tile
    float4 a = xsrc[t];
    float4 b = xsrc[t+256];
    ((float4*)xs)[t]     = a;
    ((float4*)xs)[t+256] = b;
  }
  __syncthreads();
  constexpr int G = 256/FOUT;
  constexpr int RPT = ROWS/G;
  int c = t % FOUT, g = t / FOUT;
  float acc[RPT];
  #pragma unroll
  for (int r=0;r<RPT;r++) acc[r]=0.f;
  for (int k=0;k<FIN;k+=4){
    float w0 = W[(k+0)*FOUT+c];
    float w1 = W[(k+1)*FOUT+c];
    float w2 = W[(k+2)*FOUT+c];
    float w3 = W[(k+3)*FOUT+c];
    #pragma unroll
    for (int r=0;r<RPT;r++){
      const float4 xv = *(const float4*)&xs[(g*RPT+r)*FIN+k];
      acc[r] = fmaf(xv.w, w3, fmaf(xv.z, w2, fmaf(xv.y, w1, fmaf(xv.x, w0, acc[r]))));
    }
  }
  #pragma unroll
  for (int r=0;r<RPT;r++)
    H[(i0 + g*RPT + r)*FOUT + c] = acc[r];
}

// ---------------- per-row attention halves ----------------
template<int F>
__global__ void k_alpha(const float* __restrict__ H, const float* __restrict__ Asrc,
                        const float* __restrict__ Adst, float* __restrict__ AS,
                        float* __restrict__ AD, int N){
  int lane = threadIdx.x & 63;
  int i = blockIdx.x*4 + (threadIdx.x >> 6);
  if (i >= N) return;
  float as = 0.f, ad = 0.f;
  #pragma unroll
  for (int c = lane; c < F; c += 64){
    float hv = H[(long)i*F + c];
    as = fmaf(hv, Asrc[c], as);
    ad = fmaf(hv, Adst[c], ad);
  }
  #pragma unroll
  for (int off=32; off; off>>=1){
    as += __shfl_xor(as, off);
    ad += __shfl_xor(ad, off);
  }
  if (lane==0){ AS[i]=as; AD[i]=ad; }
}

// ---------------- fused segment softmax + weighted aggregation ----------------
// one wave per destination node; self-loop handled explicitly
template<int F>
__global__ void k_agg(const float* __restrict__ H, const float* __restrict__ AS,
                      const float* __restrict__ AD, const float* __restrict__ B,
                      const int* __restrict__ offs, const int* __restrict__ deg,
                      const int* __restrict__ adj, float* __restrict__ OUT, int N){
  int lane = threadIdx.x & 63;
  int i = blockIdx.x*4 + (threadIdx.x >> 6);
  if (i >= N) return;
  int start = offs[i], dg = deg[i];
  float ad = AD[i];
  float lr_self = lrelu(AS[i] + ad);
  // pass A: online (m, d) per lane over this node's real edges
  float m = -1e30f, dacc = 0.f;
  for (int b0=0; b0<dg; b0+=64){
    int k = b0 + lane;
    if (k < dg){
      int s = adj[start+k];
      float lr = lrelu(AS[s] + ad);
      float mn = fmaxf(m, lr);
      dacc = dacc*__expf(m-mn) + __expf(lr-mn);
      m = mn;
    }
  }
  #pragma unroll
  for (int off=32; off; off>>=1){
    float m2 = __shfl_xor(m, off);
    float d2 = __shfl_xor(dacc, off);
    float mn = fmaxf(m, m2);
    dacc = dacc*__expf(m-mn) + d2*__expf(m2-mn);
    m = mn;
  }
  float M = fmaxf(m, lr_self);
  float D = dacc*__expf(m-M) + __expf(lr_self-M);
  float invD = 1.f/D;
  // pass B: weighted gather-accumulate (self + edges)
  float wself = __expf(lr_self-M)*invD;
  float acc0 = wself * H[(long)i*F + lane];
  float acc1 = 0.f;
  if (F==128) acc1 = wself * H[(long)i*F + 64 + lane];
  for (int b0=0; b0<dg; b0+=64){
    int k = b0 + lane;
    int sreg = 0; float wreg = 0.f;
    if (k < dg){
      sreg = adj[start+k];
      wreg = __expf(lrelu(AS[sreg]+ad) - M)*invD;
    }
    int cnt = min(64, dg-b0);
    int kk = 0;
    for (; kk+4<=cnt; kk+=4){
      int   s0=__shfl(sreg,kk),   s1=__shfl(sreg,kk+1),   s2=__shfl(sreg,kk+2),   s3=__shfl(sreg,kk+3);
      float w0=__shfl(wreg,kk),   w1=__shfl(wreg,kk+1),   w2=__shfl(wreg,kk+2),   w3=__shfl(wreg,kk+3);
      float h0 = H[(long)s0*F+lane];
      float h1 = H[(long)s1*F+lane];
      float h2 = H[(long)s2*F+lane];
      float h3 = H[(long)s3*F+lane];
      acc0 += w0*h0 + w1*h1 + w2*h2 + w3*h3;
      if (F==128){
        float g0 = H[(long)s0*F+64+lane];
        float g1 = H[(long)s1*F+64+lane];
        float g2 = H[(long)s2*F+64+lane];
        float g3 = H[(long)s3*F+64+lane];
        acc1 += w0*g0 + w1*g1 + w2*g2 + w3*g3;
      }
    }
    for (; kk<cnt; kk++){
      int s0=__shfl(sreg,kk); float w0=__shfl(wreg,kk);
      acc0 += w0*H[(long)s0*F+lane];
      if (F==128) acc1 += w0*H[(long)s0*F+64+lane];
    }
  }
  float o0 = fmaxf(acc0 + B[lane], 0.f);
  OUT[(long)i*F+lane] = o0;
  if (F==128){
    float o1 = fmaxf(acc1 + B[64+lane], 0.f);
    OUT[(long)i*F+64+lane] = o1;
  }
}

// ---------------- fused VAE head (f32 in, f32 outputs) ----------------
__global__ void k_head(const float* __restrict__ H2, const float* __restrict__ EPS,
                       const float* __restrict__ Wmu, const float* __restrict__ bmu,
                       const float* __restrict__ Wlv, const float* __restrict__ blv,
                       const float* __restrict__ Wd1, const float* __restrict__ bd1,
                       const float* __restrict__ Wd2, const float* __restrict__ bd2,
                       float* __restrict__ out_recon, float* __restrict__ out_mu,
                       float* __restrict__ out_lv, int N){
  constexpr int ROWS=16;
  __shared__ float h2s[ROWS*64];
  __shared__ float zs[ROWS*64];
  __shared__ float ds[ROWS*128];
  int t = threadIdx.x;
  long i0 = (long)blockIdx.x*ROWS;
  {
    const float4* s4 = (const float4*)(H2 + i0*64);  // 256 float4s per tile
    ((float4*)h2s)[t] = s4[t];
  }
  __syncthreads();
  // phase 1: mu, logvar, z
  {
    int c = t & 63, q = t >> 6;     // 4 groups x 4 rows
    float am[4] = {0,0,0,0}, av[4] = {0,0,0,0};
    for (int k=0;k<64;k++){
      float wm = Wmu[k*64+c];
      float wv = Wlv[k*64+c];
      #pragma unroll
      for (int r=0;r<4;r++){
        float h = h2s[(q*4+r)*64 + k];
        am[r] = fmaf(h, wm, am[r]);
        av[r] = fmaf(h, wv, av[r]);
      }
    }
    float bm = bmu[c], bv = blv[c];
    #pragma unroll
    for (int r=0;r<4;r++){
      int row = q*4+r; long i = i0 + row;
      float mu = am[r] + bm;
      float lv = av[r] + bv;
      out_mu[i*64+c] = mu;
      out_lv[i*64+c] = lv;
      zs[row*64+c] = fmaf(EPS[i*64+c], __expf(0.5f*lv), mu);
    }
  }
  __syncthreads();
  // phase 2: d = relu(z @ Wd1 + bd1)
  {
    int c = t & 127, q = t >> 7;    // 2 groups x 8 rows
    float accd[8] = {0,0,0,0,0,0,0,0};
    for (int k=0;k<64;k++){
      float w = Wd1[k*128+c];
      #pragma unroll
      for (int r=0;r<8;r++)
        accd[r] = fmaf(zs[(q*8+r)*64+k], w, accd[r]);
    }
    float bb = bd1[c];
    #pragma unroll
    for (int r=0;r<8;r++)
      ds[(q*8+r)*128+c] = fmaxf(accd[r]+bb, 0.f);
  }
  __syncthreads();
  // phase 3: recon = sigmoid(d @ Wd2 + bd2)
  {
    int c = t & 127, q = t >> 7;
    float accr[8] = {0,0,0,0,0,0,0,0};
    for (int k=0;k<128;k++){
      float w = Wd2[k*128+c];
      #pragma unroll
      for (int r=0;r<8;r++)
        accr[r] = fmaf(ds[(q*8+r)*128+k], w, accr[r]);
    }
    float bb = bd2[c];
    #pragma unroll
    for (int r=0;r<8;r++){
      long i = i0 + q*8 + r;
      float v = accr[r] + bb;
      out_recon[i*128+c] = 1.f/(1.f+__expf(-v));
    }
  }
}

extern "C" void kernel_launch(void* const* d_in, const int* in_sizes, int n_in,
                              void* d_out, int out_size, void* d_ws, size_t ws_size,
                              hipStream_t stream){
  const float* x    = (const float*)d_in[0];
  const int*   ei   = (const int*)  d_in[1];
  const float* eps  = (const float*)d_in[2];
  const float* W1   = (const float*)d_in[3];
  const float* as1v = (const float*)d_in[4];
  const float* ad1v = (const float*)d_in[5];
  const float* b1   = (const float*)d_in[6];
  const float* W2   = (const float*)d_in[7];
  const float* as2v = (const float*)d_in[8];
  const float* ad2v = (const float*)d_in[9];
  const float* b2   = (const float*)d_in[10];
  const float* Wmu  = (const float*)d_in[11];
  const float* bmu  = (const float*)d_in[12];
  const float* Wlv  = (const float*)d_in[13];
  const float* blv  = (const float*)d_in[14];
  const float* Wd1  = (const float*)d_in[15];
  const float* bd1  = (const float*)d_in[16];
  const float* Wd2  = (const float*)d_in[17];
  const float* bd2  = (const float*)d_in[18];

  const int N = in_sizes[0] / 128;   // 50000
  const int E = in_sizes[1] / 2;     // 800000
  const int* esrc = ei;
  const int* edst = ei + E;

  char* wp = (char*)d_ws;
  auto alloc = [&](size_t bytes)->char*{
    char* p = wp; wp += (bytes + 255) & ~(size_t)255; return p;
  };
  int*   deg  = (int*)  alloc((size_t)N*4);
  int*   offs = (int*)  alloc((size_t)N*4);
  int*   cur  = (int*)  alloc((size_t)N*4);
  int*   bsum = (int*)  alloc(256*4);
  int*   adj  = (int*)  alloc((size_t)E*4);
  float* h1   = (float*)alloc((size_t)N*128*4);
  float* o1   = (float*)alloc((size_t)N*128*4);
  float* AS1  = (float*)alloc((size_t)N*4);
  float* AD1  = (float*)alloc((size_t)N*4);
  float* AS2  = (float*)alloc((size_t)N*4);
  float* AD2  = (float*)alloc((size_t)N*4);
  // h2/o2 alias h1's space (h1 is dead once k_gemm<64> runs)
  float* h2 = h1;
  float* o2 = h1 + (size_t)N*64;
  (void)ws_size; (void)n_in; (void)out_size;

  float* out_recon = (float*)d_out;
  float* out_mu    = out_recon + (size_t)N*128;
  float* out_lv    = out_mu    + (size_t)N*64;

  hipMemsetAsync(deg, 0, (size_t)N*4, stream);
  int eb = (E + 255)/256;
  int nb = (N + 1023)/1024;
  k_hist   <<<eb, 256, 0, stream>>>(edst, deg, E);
  k_scan1  <<<nb, 256, 0, stream>>>(deg, offs, bsum, N);
  k_scan2  <<<1,   64, 0, stream>>>(bsum, nb);
  k_scan3  <<<(N+255)/256, 256, 0, stream>>>(offs, cur, bsum, N);
  k_scatter<<<eb, 256, 0, stream>>>(esrc, edst, cur, adj, E);

  int gb = N/16;       // 3125 (N % 16 == 0)
  int wb = (N+3)/4;    // 12500 (wave per node, 4 waves/block)
  k_gemm<128> <<<gb, 256, 0, stream>>>(x, W1, h1, N);
  k_alpha<128><<<wb, 256, 0, stream>>>(h1, as1v, ad1v, AS1, AD1, N);
  k_agg<128>  <<<wb, 256, 0, stream>>>(h1, AS1, AD1, b1, offs, deg, adj, o1, N);
  k_gemm<64>  <<<gb, 256, 0, stream>>>(o1, W2, h2, N);
  k_alpha<64> <<<wb, 256, 0, stream>>>(h2, as2v, ad2v, AS2, AD2, N);
  k_agg<64>   <<<wb, 256, 0, stream>>>(h2, AS2, AD2, b2, offs, deg, adj, o2, N);
  k_head      <<<gb, 256, 0, stream>>>(o2, eps, Wmu, bmu, Wlv, blv, Wd1, bd1, Wd2, bd2,
                                       out_recon, out_mu, out_lv, N);
}